// Round 2
// baseline (228.141 us; speedup 1.0000x reference)
//
#include <hip/hip_runtime.h>

// WaveletFeatureExtractor: db4 wavedec (5 levels, symmetric pad) -> adaptive pool 128
// -> per-level 128x128 MLP (ReLU) -> fused 640->512 MLP (ReLU).
//
// Kernel 1 (dwt_pool): one block (512 thr) per batch row.
//  - Level 1 (low-pass only; cD1 is dead) straight from global, 4 outputs/thread,
//    4x float4 loads covering the shared 16-float window.
//  - Levels 2..5 in LDS ping-pong (bufA/bufB); cD bands pooled ON THE FLY via
//    ds atomicAdd into a 640-float accumulator (torch adaptive-pool bucket math,
//    compile-time n -> magic-mul). Level 5 stores nothing. No bufD.
//  - Interior outputs take a symfold-free fast path; only ~10 boundary groups/level
//    take the folding path.
//  LDS = 8195 + 4101 + 640 floats = 51.7 KB -> 3 blocks/CU, 24 waves (75%).
// Kernel 2 (mlp): unchanged from round 1 (8-row weight-reuse blocking).

#define BATCH   2048
#define SIGLEN  16384
#define N1      8195
#define N2      4101
#define N3      2054
#define N4      1030
#define N5      518
#define POOLP   128
#define COMB    640   // 5 * 128
#define OUTD    512
#define NTHR    512

// Reversed db4 decomposition filters (reference flips filt[:, ::-1] -> correlation)
__device__ constexpr float LO[8] = {
     0.2303778133088965f,   0.7148465705529157f,   0.6308807679298589f,
    -0.027983769416859854f, -0.18703481171909309f,  0.030841381835560764f,
     0.0328830116668852f,  -0.010597401785069032f };
__device__ constexpr float HI[8] = {
    -0.010597401785069032f, -0.0328830116668852f,   0.030841381835560764f,
     0.18703481171909309f,  -0.027983769416859854f, -0.6308807679298589f,
     0.7148465705529157f,  -0.2303778133088965f };

// Scatter one value of an M-long band into the 128-bucket adaptive-pool accumulator.
// torch: starts[p] = p*M//128, ends[p] = ((p+1)*M+127)//128 -> buckets overlap by <=1.
template<int M>
__device__ __forceinline__ void pool_add(float* __restrict__ acc, int j, float v) {
    const int p = (j * 128) / M;               // M is constexpr -> magic mul
    atomicAdd(&acc[p], v);
    const int snext = ((p + 1) * M) >> 7;      // start of bucket p+1
    if ((p + 1 < 128) && (j >= snext)) atomicAdd(&acc[p + 1], v);
}

// One LDS->LDS DWT level. N = src length, M = out length.
// Stores cA (if STORE_A); pools cD into slot DLVL, and cA into ALVL if >=0.
template<int N, int M, bool STORE_A, int DLVL, int ALVL>
__device__ __forceinline__ void dwt_level_lds(const float* __restrict__ src,
                                              float* __restrict__ dstA,
                                              float* __restrict__ pacc,
                                              int tid) {
    for (int j0 = tid * 4; j0 < M; j0 += NTHR * 4) {
        if ((j0 >= 4) && (2 * j0 + 7 <= N - 1) && (j0 + 4 <= M)) {
            // fast path: aligned 16-float window [2*j0-8, 2*j0+7]
            const float4* s4 = reinterpret_cast<const float4*>(src + 2 * j0 - 8);
            const float4 v0 = s4[0], v1 = s4[1], v2 = s4[2], v3 = s4[3];
            float w[16];
            w[0]=v0.x;  w[1]=v0.y;  w[2]=v0.z;  w[3]=v0.w;
            w[4]=v1.x;  w[5]=v1.y;  w[6]=v1.z;  w[7]=v1.w;
            w[8]=v2.x;  w[9]=v2.y;  w[10]=v2.z; w[11]=v2.w;
            w[12]=v3.x; w[13]=v3.y; w[14]=v3.z; w[15]=v3.w;
            float a[4], d[4];
#pragma unroll
            for (int k = 0; k < 4; ++k) {
                float aa = 0.f, dd = 0.f;
#pragma unroll
                for (int t = 0; t < 8; ++t) {
                    const float v = w[2 + 2 * k + t];
                    aa = fmaf(v, LO[t], aa);
                    dd = fmaf(v, HI[t], dd);
                }
                a[k] = aa; d[k] = dd;
            }
            if constexpr (STORE_A)
                *reinterpret_cast<float4*>(dstA + j0) = make_float4(a[0], a[1], a[2], a[3]);
#pragma unroll
            for (int k = 0; k < 4; ++k) {
                pool_add<M>(pacc + DLVL * POOLP, j0 + k, d[k]);
                if constexpr (ALVL >= 0) pool_add<M>(pacc + ALVL * POOLP, j0 + k, a[k]);
            }
        } else {
            // boundary / tail path with symmetric folding
            for (int k = 0; k < 4; ++k) {
                const int j = j0 + k;
                if (j >= M) break;
                float aa = 0.f, dd = 0.f;
#pragma unroll
                for (int t = 0; t < 8; ++t) {
                    int idx = 2 * j - 6 + t;
                    idx = (idx < 0) ? (-1 - idx) : idx;
                    idx = (idx >= N) ? (2 * N - 1 - idx) : idx;
                    const float v = src[idx];
                    aa = fmaf(v, LO[t], aa);
                    dd = fmaf(v, HI[t], dd);
                }
                if constexpr (STORE_A) dstA[j] = aa;
                pool_add<M>(pacc + DLVL * POOLP, j, dd);
                if constexpr (ALVL >= 0) pool_add<M>(pacc + ALVL * POOLP, j, aa);
            }
        }
    }
}

__global__ __launch_bounds__(NTHR, 6) void dwt_pool_kernel(const float* __restrict__ x,
                                                           float* __restrict__ pooled) {
    __shared__ __align__(16) float bufA[N1];   // cA1 / cA3
    __shared__ __align__(16) float bufB[N2];   // cA2 / cA4
    __shared__ float pacc[COMB];               // pooled-sum accumulators

    const int tid = threadIdx.x;
    const int row = blockIdx.x;
    const float* __restrict__ xr = x + (size_t)row * SIGLEN;

    for (int i = tid; i < COMB; i += NTHR) pacc[i] = 0.f;

    // Level 1: global -> bufA (low-pass only)
    for (int j0 = tid * 4; j0 < N1; j0 += NTHR * 4) {
        if ((j0 >= 4) && (2 * j0 + 7 <= SIGLEN - 1) && (j0 + 4 <= N1)) {
            const float4* s4 = reinterpret_cast<const float4*>(xr + 2 * j0 - 8);
            const float4 v0 = s4[0], v1 = s4[1], v2 = s4[2], v3 = s4[3];
            float w[16];
            w[0]=v0.x;  w[1]=v0.y;  w[2]=v0.z;  w[3]=v0.w;
            w[4]=v1.x;  w[5]=v1.y;  w[6]=v1.z;  w[7]=v1.w;
            w[8]=v2.x;  w[9]=v2.y;  w[10]=v2.z; w[11]=v2.w;
            w[12]=v3.x; w[13]=v3.y; w[14]=v3.z; w[15]=v3.w;
            float a[4];
#pragma unroll
            for (int k = 0; k < 4; ++k) {
                float aa = 0.f;
#pragma unroll
                for (int t = 0; t < 8; ++t) aa = fmaf(w[2 + 2 * k + t], LO[t], aa);
                a[k] = aa;
            }
            *reinterpret_cast<float4*>(bufA + j0) = make_float4(a[0], a[1], a[2], a[3]);
        } else {
            for (int k = 0; k < 4; ++k) {
                const int j = j0 + k;
                if (j >= N1) break;
                float aa = 0.f;
#pragma unroll
                for (int t = 0; t < 8; ++t) {
                    int idx = 2 * j - 6 + t;
                    idx = (idx < 0) ? (-1 - idx) : idx;
                    idx = (idx >= SIGLEN) ? (2 * SIGLEN - 1 - idx) : idx;
                    aa = fmaf(xr[idx], LO[t], aa);
                }
                bufA[j] = aa;
            }
        }
    }
    __syncthreads();

    dwt_level_lds<N1, N2, true,  4, -1>(bufA, bufB, pacc, tid);  // cD2 -> slot 4
    __syncthreads();
    dwt_level_lds<N2, N3, true,  3, -1>(bufB, bufA, pacc, tid);  // cD3 -> slot 3
    __syncthreads();
    dwt_level_lds<N3, N4, true,  2, -1>(bufA, bufB, pacc, tid);  // cD4 -> slot 2
    __syncthreads();
    dwt_level_lds<N4, N5, false, 1,  0>(bufB, bufA, pacc, tid);  // cD5 -> 1, cA5 -> 0
    __syncthreads();

    // Finalize: divide bucket sums by bucket widths, write pooled[row][640]
    float* __restrict__ pr = pooled + (size_t)row * COMB;
    for (int c = tid; c < COMB; c += NTHR) {
        const int l = c >> 7, p = c & 127;
        const int n = (l <= 1) ? N5 : (l == 2 ? N4 : (l == 3 ? N3 : N2));
        const int s = (p * n) >> 7;
        const int e = ((p + 1) * n + 127) >> 7;
        pr[c] = pacc[c] / (float)(e - s);
    }
}

constexpr int MLP_R = 8;  // rows per block

__global__ __launch_bounds__(256) void mlp_kernel(const float* __restrict__ pooled,
                                                  const float* __restrict__ lw,  // [5][128][128]
                                                  const float* __restrict__ lb,  // [5][128]
                                                  const float* __restrict__ fw,  // [512][640]
                                                  const float* __restrict__ fb,  // [512]
                                                  float* __restrict__ out) {     // [B][512]
    __shared__ float sp[MLP_R][COMB];  // pooled tile
    __shared__ float sc[MLP_R][COMB];  // comb (post level-net ReLU) tile

    const int tid = threadIdx.x;
    const int r0 = blockIdx.x * MLP_R;

    for (int i = tid; i < MLP_R * COMB; i += 256) {
        (&sp[0][0])[i] = pooled[(size_t)r0 * COMB + i];
    }
    __syncthreads();

    // Level nets: comb[r][c] = relu(dot(sp[r][l*128..], lw[c][:]) + lb[c])
    for (int c = tid; c < COMB; c += 256) {
        const float* __restrict__ w = lw + (size_t)c * POOLP;
        const int lbase = (c >> 7) << 7;
        const float bias = lb[c];
        float acc[MLP_R];
#pragma unroll
        for (int r = 0; r < MLP_R; ++r) acc[r] = bias;
        for (int t = 0; t < POOLP; t += 4) {
            const float4 wv = *reinterpret_cast<const float4*>(w + t);
#pragma unroll
            for (int r = 0; r < MLP_R; ++r) {
                const float4 pv = *reinterpret_cast<const float4*>(&sp[r][lbase + t]);
                acc[r] += pv.x * wv.x + pv.y * wv.y + pv.z * wv.z + pv.w * wv.w;
            }
        }
#pragma unroll
        for (int r = 0; r < MLP_R; ++r) sc[r][c] = fmaxf(acc[r], 0.f);
    }
    __syncthreads();

    // Fusion: out[r][j] = relu(dot(sc[r][:], fw[j][:]) + fb[j])
    for (int j = tid; j < OUTD; j += 256) {
        const float* __restrict__ w = fw + (size_t)j * COMB;
        const float bias = fb[j];
        float acc[MLP_R];
#pragma unroll
        for (int r = 0; r < MLP_R; ++r) acc[r] = bias;
        for (int t = 0; t < COMB; t += 4) {
            const float4 wv = *reinterpret_cast<const float4*>(w + t);
#pragma unroll
            for (int r = 0; r < MLP_R; ++r) {
                const float4 cv = *reinterpret_cast<const float4*>(&sc[r][t]);
                acc[r] += cv.x * wv.x + cv.y * wv.y + cv.z * wv.z + cv.w * wv.w;
            }
        }
#pragma unroll
        for (int r = 0; r < MLP_R; ++r) {
            out[(size_t)(r0 + r) * OUTD + j] = fmaxf(acc[r], 0.f);
        }
    }
}

extern "C" void kernel_launch(void* const* d_in, const int* in_sizes, int n_in,
                              void* d_out, int out_size, void* d_ws, size_t ws_size,
                              hipStream_t stream) {
    const float* x  = (const float*)d_in[0];  // [2048][16384]
    const float* lw = (const float*)d_in[1];  // [5][128][128]
    const float* lb = (const float*)d_in[2];  // [5][128]
    const float* fw = (const float*)d_in[3];  // [512][640]
    const float* fb = (const float*)d_in[4];  // [512]
    float* out = (float*)d_out;               // [2048][512]

    float* pooled = (float*)d_ws;             // [2048][640] fp32 = 5.24 MB

    dwt_pool_kernel<<<BATCH, NTHR, 0, stream>>>(x, pooled);
    mlp_kernel<<<BATCH / MLP_R, 256, 0, stream>>>(pooled, lw, lb, fw, fb, out);
}

// Round 3
// 131.617 us; speedup vs baseline: 1.7334x; 1.7334x over previous
//
#include <hip/hip_runtime.h>

// WaveletFeatureExtractor: db4 wavedec (5 levels, symmetric pad) -> adaptive pool 128
// -> per-level 128x128 MLP (ReLU) -> fused 640->512 MLP (ReLU).
//
// Round 3: round-2's vectorized fast-path DWT (4 outputs/thread, float4 window
// loads, symfold only at boundaries) WITHOUT the LDS-atomic pooling that
// serialized round 2 (32-way same-bucket contention -> VALUBusy 14%).
// cD goes to bufD via float4 stores; pooling is a separate contention-free pass:
// 4 threads per bucket, stride-4 partials + 2x shfl_xor, direct global write.
// LDS = 8195 + 4101 + 4101 floats = 65.6 KB -> 2 blocks/CU.

#define BATCH   2048
#define SIGLEN  16384
#define N1      8195
#define N2      4101
#define N3      2054
#define N4      1030
#define N5      518
#define POOLP   128
#define COMB    640   // 5 * 128
#define OUTD    512
#define NTHR    512

// Reversed db4 decomposition filters (reference flips filt[:, ::-1] -> correlation)
__device__ constexpr float LO[8] = {
     0.2303778133088965f,   0.7148465705529157f,   0.6308807679298589f,
    -0.027983769416859854f, -0.18703481171909309f,  0.030841381835560764f,
     0.0328830116668852f,  -0.010597401785069032f };
__device__ constexpr float HI[8] = {
    -0.010597401785069032f, -0.0328830116668852f,   0.030841381835560764f,
     0.18703481171909309f,  -0.027983769416859854f, -0.6308807679298589f,
     0.7148465705529157f,  -0.2303778133088965f };

// One LDS->LDS DWT level. N = src length, M = out length. Writes cA and cD.
template<int N, int M>
__device__ __forceinline__ void dwt_level_lds(const float* __restrict__ src,
                                              float* __restrict__ dstA,
                                              float* __restrict__ dstD,
                                              int tid) {
    for (int j0 = tid * 4; j0 < M; j0 += NTHR * 4) {
        if ((j0 >= 4) && (2 * j0 + 7 <= N - 1) && (j0 + 4 <= M)) {
            // fast path: 16-float window [2*j0-8, 2*j0+7] covers outputs j0..j0+3
            const float4* s4 = reinterpret_cast<const float4*>(src + 2 * j0 - 8);
            const float4 v0 = s4[0], v1 = s4[1], v2 = s4[2], v3 = s4[3];
            float w[16];
            w[0]=v0.x;  w[1]=v0.y;  w[2]=v0.z;  w[3]=v0.w;
            w[4]=v1.x;  w[5]=v1.y;  w[6]=v1.z;  w[7]=v1.w;
            w[8]=v2.x;  w[9]=v2.y;  w[10]=v2.z; w[11]=v2.w;
            w[12]=v3.x; w[13]=v3.y; w[14]=v3.z; w[15]=v3.w;
            float a[4], d[4];
#pragma unroll
            for (int k = 0; k < 4; ++k) {
                float aa = 0.f, dd = 0.f;
#pragma unroll
                for (int t = 0; t < 8; ++t) {
                    const float v = w[2 + 2 * k + t];
                    aa = fmaf(v, LO[t], aa);
                    dd = fmaf(v, HI[t], dd);
                }
                a[k] = aa; d[k] = dd;
            }
            *reinterpret_cast<float4*>(dstA + j0) = make_float4(a[0], a[1], a[2], a[3]);
            *reinterpret_cast<float4*>(dstD + j0) = make_float4(d[0], d[1], d[2], d[3]);
        } else {
            // boundary / tail path with symmetric folding
            for (int k = 0; k < 4; ++k) {
                const int j = j0 + k;
                if (j >= M) break;
                float aa = 0.f, dd = 0.f;
#pragma unroll
                for (int t = 0; t < 8; ++t) {
                    int idx = 2 * j - 6 + t;
                    idx = (idx < 0) ? (-1 - idx) : idx;
                    idx = (idx >= N) ? (2 * N - 1 - idx) : idx;
                    const float v = src[idx];
                    aa = fmaf(v, LO[t], aa);
                    dd = fmaf(v, HI[t], dd);
                }
                dstA[j] = aa;
                dstD[j] = dd;
            }
        }
    }
}

// Contention-free adaptive pool: 4 threads per bucket, stride-4 partials,
// combine via shfl_xor within the 4-lane group, lane 0 writes the mean.
template<int M, int SLOT>
__device__ __forceinline__ void pool_band(const float* __restrict__ buf,
                                          float* __restrict__ pr, int tid) {
    const int p = tid >> 2, sub = tid & 3;
    const int s = (p * M) >> 7;
    const int e = ((p + 1) * M + 127) >> 7;
    float acc = 0.f;
    for (int t = s + sub; t < e; t += 4) acc += buf[t];
    acc += __shfl_xor(acc, 1);
    acc += __shfl_xor(acc, 2);
    if (sub == 0) pr[SLOT * POOLP + p] = acc / (float)(e - s);
}

__global__ __launch_bounds__(NTHR, 4) void dwt_pool_kernel(const float* __restrict__ x,
                                                           float* __restrict__ pooled) {
    __shared__ __align__(16) float bufA[N1];   // cA1 / cA3 / cA5
    __shared__ __align__(16) float bufB[N2];   // cA2 / cA4
    __shared__ __align__(16) float bufD[N2];   // cD scratch per level

    const int tid = threadIdx.x;
    const int row = blockIdx.x;
    const float* __restrict__ xr = x + (size_t)row * SIGLEN;
    float* __restrict__ pr = pooled + (size_t)row * COMB;

    // Level 1: global -> bufA (low-pass only; cD1 is dead in the reference forward)
    for (int j0 = tid * 4; j0 < N1; j0 += NTHR * 4) {
        if ((j0 >= 4) && (2 * j0 + 7 <= SIGLEN - 1) && (j0 + 4 <= N1)) {
            const float4* s4 = reinterpret_cast<const float4*>(xr + 2 * j0 - 8);
            const float4 v0 = s4[0], v1 = s4[1], v2 = s4[2], v3 = s4[3];
            float w[16];
            w[0]=v0.x;  w[1]=v0.y;  w[2]=v0.z;  w[3]=v0.w;
            w[4]=v1.x;  w[5]=v1.y;  w[6]=v1.z;  w[7]=v1.w;
            w[8]=v2.x;  w[9]=v2.y;  w[10]=v2.z; w[11]=v2.w;
            w[12]=v3.x; w[13]=v3.y; w[14]=v3.z; w[15]=v3.w;
            float a[4];
#pragma unroll
            for (int k = 0; k < 4; ++k) {
                float aa = 0.f;
#pragma unroll
                for (int t = 0; t < 8; ++t) aa = fmaf(w[2 + 2 * k + t], LO[t], aa);
                a[k] = aa;
            }
            *reinterpret_cast<float4*>(bufA + j0) = make_float4(a[0], a[1], a[2], a[3]);
        } else {
            for (int k = 0; k < 4; ++k) {
                const int j = j0 + k;
                if (j >= N1) break;
                float aa = 0.f;
#pragma unroll
                for (int t = 0; t < 8; ++t) {
                    int idx = 2 * j - 6 + t;
                    idx = (idx < 0) ? (-1 - idx) : idx;
                    idx = (idx >= SIGLEN) ? (2 * SIGLEN - 1 - idx) : idx;
                    aa = fmaf(xr[idx], LO[t], aa);
                }
                bufA[j] = aa;
            }
        }
    }
    __syncthreads();

    // Level 2: bufA(8195) -> cA2 bufB, cD2 bufD
    dwt_level_lds<N1, N2>(bufA, bufB, bufD, tid);
    __syncthreads();
    pool_band<N2, 4>(bufD, pr, tid);           // coeffs[4] = cD2
    __syncthreads();

    // Level 3: bufB(4101) -> cA3 bufA, cD3 bufD
    dwt_level_lds<N2, N3>(bufB, bufA, bufD, tid);
    __syncthreads();
    pool_band<N3, 3>(bufD, pr, tid);           // coeffs[3] = cD3
    __syncthreads();

    // Level 4: bufA(2054) -> cA4 bufB, cD4 bufD
    dwt_level_lds<N3, N4>(bufA, bufB, bufD, tid);
    __syncthreads();
    pool_band<N4, 2>(bufD, pr, tid);           // coeffs[2] = cD4
    __syncthreads();

    // Level 5: bufB(1030) -> cA5 bufA, cD5 bufD
    dwt_level_lds<N4, N5>(bufB, bufA, bufD, tid);
    __syncthreads();
    pool_band<N5, 0>(bufA, pr, tid);           // coeffs[0] = cA5
    pool_band<N5, 1>(bufD, pr, tid);           // coeffs[1] = cD5
}

constexpr int MLP_R = 8;  // rows per block

__global__ __launch_bounds__(256) void mlp_kernel(const float* __restrict__ pooled,
                                                  const float* __restrict__ lw,  // [5][128][128]
                                                  const float* __restrict__ lb,  // [5][128]
                                                  const float* __restrict__ fw,  // [512][640]
                                                  const float* __restrict__ fb,  // [512]
                                                  float* __restrict__ out) {     // [B][512]
    __shared__ float sp[MLP_R][COMB];  // pooled tile
    __shared__ float sc[MLP_R][COMB];  // comb (post level-net ReLU) tile

    const int tid = threadIdx.x;
    const int r0 = blockIdx.x * MLP_R;

    for (int i = tid; i < MLP_R * COMB; i += 256) {
        (&sp[0][0])[i] = pooled[(size_t)r0 * COMB + i];
    }
    __syncthreads();

    // Level nets: comb[r][c] = relu(dot(sp[r][l*128..], lw[c][:]) + lb[c])
    for (int c = tid; c < COMB; c += 256) {
        const float* __restrict__ w = lw + (size_t)c * POOLP;
        const int lbase = (c >> 7) << 7;
        const float bias = lb[c];
        float acc[MLP_R];
#pragma unroll
        for (int r = 0; r < MLP_R; ++r) acc[r] = bias;
        for (int t = 0; t < POOLP; t += 4) {
            const float4 wv = *reinterpret_cast<const float4*>(w + t);
#pragma unroll
            for (int r = 0; r < MLP_R; ++r) {
                const float4 pv = *reinterpret_cast<const float4*>(&sp[r][lbase + t]);
                acc[r] += pv.x * wv.x + pv.y * wv.y + pv.z * wv.z + pv.w * wv.w;
            }
        }
#pragma unroll
        for (int r = 0; r < MLP_R; ++r) sc[r][c] = fmaxf(acc[r], 0.f);
    }
    __syncthreads();

    // Fusion: out[r][j] = relu(dot(sc[r][:], fw[j][:]) + fb[j])
    for (int j = tid; j < OUTD; j += 256) {
        const float* __restrict__ w = fw + (size_t)j * COMB;
        const float bias = fb[j];
        float acc[MLP_R];
#pragma unroll
        for (int r = 0; r < MLP_R; ++r) acc[r] = bias;
        for (int t = 0; t < COMB; t += 4) {
            const float4 wv = *reinterpret_cast<const float4*>(w + t);
#pragma unroll
            for (int r = 0; r < MLP_R; ++r) {
                const float4 cv = *reinterpret_cast<const float4*>(&sc[r][t]);
                acc[r] += cv.x * wv.x + cv.y * wv.y + cv.z * wv.z + cv.w * wv.w;
            }
        }
#pragma unroll
        for (int r = 0; r < MLP_R; ++r) {
            out[(size_t)(r0 + r) * OUTD + j] = fmaxf(acc[r], 0.f);
        }
    }
}

extern "C" void kernel_launch(void* const* d_in, const int* in_sizes, int n_in,
                              void* d_out, int out_size, void* d_ws, size_t ws_size,
                              hipStream_t stream) {
    const float* x  = (const float*)d_in[0];  // [2048][16384]
    const float* lw = (const float*)d_in[1];  // [5][128][128]
    const float* lb = (const float*)d_in[2];  // [5][128]
    const float* fw = (const float*)d_in[3];  // [512][640]
    const float* fb = (const float*)d_in[4];  // [512]
    float* out = (float*)d_out;               // [2048][512]

    float* pooled = (float*)d_ws;             // [2048][640] fp32 = 5.24 MB

    dwt_pool_kernel<<<BATCH, NTHR, 0, stream>>>(x, pooled);
    mlp_kernel<<<BATCH / MLP_R, 256, 0, stream>>>(pooled, lw, lb, fw, fb, out);
}